// Round 1
// baseline (394.078 us; speedup 1.0000x reference)
//
#include <hip/hip_runtime.h>
#include <math.h>

#define NROWS 524288
#define LATENT 64
#define NUM_CODES 1024
#define BLOCK 256
#define GRID 1024
#define ROWS_PER_BLOCK (NROWS / GRID)   // 512

// Quantize one component: returns centered value, sets bin.
__device__ __forceinline__ float fsq_quant(float s, float Lm1, int& bin) {
    float t  = tanhf(s);
    float zs = (t + 1.0f) * 0.5f * Lm1;   // z_unit * (L-1)
    float r  = rintf(zs);                 // round half-to-even, matches jnp.round
    r = fminf(fmaxf(r, 0.0f), Lm1);
    bin = (int)r;
    return r - Lm1 * 0.5f;
}

__global__ __launch_bounds__(BLOCK) void fsq_main(
    const float* __restrict__ z_e,    // (B, 64)
    const float* __restrict__ W_in,   // (4, 64) row-major
    const float* __restrict__ W_out,  // (64, 4) row-major
    float* __restrict__ z_q,          // (B, 64)
    float* __restrict__ idx_out,      // (B) stored as float
    unsigned int* __restrict__ hist,  // per-block (GRID*1024) or shared (1024)
    int atomic_flush)
{
    __shared__ unsigned int lhist[NUM_CODES];
    const int tid = threadIdx.x;
    for (int i = tid; i < NUM_CODES; i += BLOCK) lhist[i] = 0;

    const int sub = tid & 15;       // column-chunk id within row
    const int l0  = sub * 4;        // first latent column this lane owns

    // Per-lane weight fragments (held in registers for the whole kernel)
    const float4 win0 = *(const float4*)(W_in + 0 * LATENT + l0);
    const float4 win1 = *(const float4*)(W_in + 1 * LATENT + l0);
    const float4 win2 = *(const float4*)(W_in + 2 * LATENT + l0);
    const float4 win3 = *(const float4*)(W_in + 3 * LATENT + l0);
    const float4 wo0  = *(const float4*)(W_out + (l0 + 0) * 4);
    const float4 wo1  = *(const float4*)(W_out + (l0 + 1) * 4);
    const float4 wo2  = *(const float4*)(W_out + (l0 + 2) * 4);
    const float4 wo3  = *(const float4*)(W_out + (l0 + 3) * 4);

    __syncthreads();

    const int row_base = blockIdx.x * ROWS_PER_BLOCK + (tid >> 4);

    for (int it = 0; it < ROWS_PER_BLOCK; it += 16) {
        const int row = row_base + it;
        const size_t off = (size_t)row * LATENT + l0;
        const float4 v = *(const float4*)(z_e + off);

        // partial dot products over this lane's 4 columns
        float s0 = fmaf(v.x, win0.x, fmaf(v.y, win0.y, fmaf(v.z, win0.z, v.w * win0.w)));
        float s1 = fmaf(v.x, win1.x, fmaf(v.y, win1.y, fmaf(v.z, win1.z, v.w * win1.w)));
        float s2 = fmaf(v.x, win2.x, fmaf(v.y, win2.y, fmaf(v.z, win2.z, v.w * win2.w)));
        float s3 = fmaf(v.x, win3.x, fmaf(v.y, win3.y, fmaf(v.z, win3.z, v.w * win3.w)));

        // butterfly reduce across the 16 lanes sharing this row
        #pragma unroll
        for (int m = 1; m < 16; m <<= 1) {
            s0 += __shfl_xor(s0, m);
            s1 += __shfl_xor(s1, m);
            s2 += __shfl_xor(s2, m);
            s3 += __shfl_xor(s3, m);
        }

        // FSQ quantization (levels 8,8,8,2)
        int b0, b1, b2, b3;
        const float c0 = fsq_quant(s0, 7.0f, b0);
        const float c1 = fsq_quant(s1, 7.0f, b1);
        const float c2 = fsq_quant(s2, 7.0f, b2);
        const float c3 = fsq_quant(s3, 1.0f, b3);

        // proj_out for this lane's 4 columns: z_q[l] = sum_f c_f * W_out[l][f]
        float4 o;
        o.x = fmaf(c0, wo0.x, fmaf(c1, wo0.y, fmaf(c2, wo0.z, c3 * wo0.w)));
        o.y = fmaf(c0, wo1.x, fmaf(c1, wo1.y, fmaf(c2, wo1.z, c3 * wo1.w)));
        o.z = fmaf(c0, wo2.x, fmaf(c1, wo2.y, fmaf(c2, wo2.z, c3 * wo2.w)));
        o.w = fmaf(c0, wo3.x, fmaf(c1, wo3.y, fmaf(c2, wo3.z, c3 * wo3.w)));
        *(float4*)(z_q + off) = o;

        if (sub == 0) {
            const int idx = b0 + 8 * b1 + 64 * b2 + 512 * b3;
            atomicAdd(&lhist[idx], 1u);
            idx_out[row] = (float)idx;
        }
    }

    __syncthreads();

    if (atomic_flush) {
        for (int i = tid; i < NUM_CODES; i += BLOCK) {
            const unsigned int c = lhist[i];
            if (c) atomicAdd(&hist[i], c);
        }
    } else {
        unsigned int* dst = hist + (size_t)blockIdx.x * NUM_CODES;
        for (int i = tid; i < NUM_CODES; i += BLOCK) dst[i] = lhist[i];
    }
}

__global__ __launch_bounds__(1024) void fsq_stats(
    const unsigned int* __restrict__ hist, int nhists,
    float* __restrict__ out_scalars)   // 4 floats
{
    const int tid = threadIdx.x;   // 1024 threads, one per code
    unsigned int c = 0;
    for (int k = 0; k < nhists; ++k) c += hist[(size_t)k * NUM_CODES + tid];

    const float p = (float)c / (float)NROWS;
    double t = (double)(p * logf(p + 1e-10f));
    int nz = (c != 0) ? 1 : 0;

    // wave (64-lane) reduction
    #pragma unroll
    for (int off = 32; off > 0; off >>= 1) {
        t  += __shfl_down(t, off);
        nz += __shfl_down(nz, off);
    }
    __shared__ double sh_t[16];
    __shared__ int    sh_nz[16];
    const int wid = tid >> 6;
    if ((tid & 63) == 0) { sh_t[wid] = t; sh_nz[wid] = nz; }
    __syncthreads();
    if (tid == 0) {
        double T = 0.0; int N = 0;
        #pragma unroll
        for (int i = 0; i < 16; ++i) { T += sh_t[i]; N += sh_nz[i]; }
        out_scalars[0] = 0.0f;                       // commitment_loss
        out_scalars[1] = 0.0f;                       // codebook_loss
        out_scalars[2] = expf((float)(-T));          // perplexity
        out_scalars[3] = (float)N / (float)NUM_CODES; // utilization
    }
}

extern "C" void kernel_launch(void* const* d_in, const int* in_sizes, int n_in,
                              void* d_out, int out_size, void* d_ws, size_t ws_size,
                              hipStream_t stream) {
    const float* z_e   = (const float*)d_in[0];
    const float* W_in  = (const float*)d_in[1];
    const float* W_out = (const float*)d_in[2];

    float* out     = (float*)d_out;
    float* zq      = out;                                  // B*64
    float* idxs    = out + (size_t)NROWS * LATENT;         // B
    float* scalars = idxs + NROWS;                         // 4
    unsigned int* ws = (unsigned int*)d_ws;

    int nhists, atomic_flush;
    if (ws_size >= (size_t)GRID * NUM_CODES * sizeof(unsigned int)) {
        nhists = GRID; atomic_flush = 0;
    } else {
        nhists = 1; atomic_flush = 1;
        hipMemsetAsync(d_ws, 0, NUM_CODES * sizeof(unsigned int), stream);
    }

    fsq_main<<<GRID, BLOCK, 0, stream>>>(z_e, W_in, W_out, zq, idxs, ws, atomic_flush);
    fsq_stats<<<1, 1024, 0, stream>>>(ws, nhists, scalars);
}

// Round 2
// 243.253 us; speedup vs baseline: 1.6200x; 1.6200x over previous
//
#include <hip/hip_runtime.h>
#include <math.h>

#define NROWS 524288
#define LATENT 64
#define NUM_CODES 1024
#define BLOCK 256
#define GRID 1024
#define ROWS_PER_BLOCK (NROWS / GRID)            // 512
#define LANES_PER_ROW 8
#define ROWS_PER_ITER (BLOCK / LANES_PER_ROW)    // 32
#define NITER (ROWS_PER_BLOCK / ROWS_PER_ITER)   // 16

typedef float v4f __attribute__((ext_vector_type(4)));

__device__ __forceinline__ v4f ldnt4(const float* p) {
    return __builtin_nontemporal_load((const v4f*)p);
}
__device__ __forceinline__ void stnt4(float* p, v4f v) {
    __builtin_nontemporal_store(v, (v4f*)p);
}

__device__ __forceinline__ float dot8(v4f a, v4f wa, v4f b, v4f wb) {
    float r = a.x * wa.x;
    r = fmaf(a.y, wa.y, r); r = fmaf(a.z, wa.z, r); r = fmaf(a.w, wa.w, r);
    r = fmaf(b.x, wb.x, r); r = fmaf(b.y, wb.y, r);
    r = fmaf(b.z, wb.z, r); r = fmaf(b.w, wb.w, r);
    return r;
}

// Quantize one level-8 component (round half-to-even matches jnp.round).
__device__ __forceinline__ float q7(float s, int& bin) {
    float t  = tanhf(s);
    float zs = (t + 1.0f) * 0.5f * 7.0f;
    float r  = rintf(zs);
    r = fminf(fmaxf(r, 0.0f), 7.0f);
    bin = (int)r;
    return r - 3.5f;
}

__global__ __launch_bounds__(BLOCK) void fsq_main(
    const float* __restrict__ z_e,    // (B, 64)
    const float* __restrict__ W_in,   // (4, 64) row-major
    const float* __restrict__ W_out,  // (64, 4) row-major
    float* __restrict__ z_q,          // (B, 64)
    float* __restrict__ idx_out,      // (B) stored as float
    unsigned int* __restrict__ counts,// (1024) final counts (zeroed here if !atomic_flush)
    unsigned int* __restrict__ hists, // (GRID, 1024) per-block partials
    int atomic_flush)
{
    __shared__ unsigned int lhist[NUM_CODES];
    const int tid = threadIdx.x;
    for (int i = tid; i < NUM_CODES; i += BLOCK) lhist[i] = 0;
    if (!atomic_flush && blockIdx.x == 0) {
        // zero the final counts buffer; reducer (next kernel) atomically adds into it
        for (int i = tid; i < NUM_CODES; i += BLOCK) counts[i] = 0;
    }

    const int sub = tid & (LANES_PER_ROW - 1);  // lane within row-group
    const int rid = tid >> 3;                   // row within iteration block (0..31)
    const int l0  = sub * 4;                    // first column of fragment A (B is +32)

    // Weight fragments held in registers.
    v4f winA[4], winB[4], woA[4], woB[4];
    #pragma unroll
    for (int f = 0; f < 4; ++f) {
        winA[f] = *(const v4f*)(W_in + f * LATENT + l0);
        winB[f] = *(const v4f*)(W_in + f * LATENT + 32 + l0);
    }
    #pragma unroll
    for (int j = 0; j < 4; ++j) {
        woA[j] = *(const v4f*)(W_out + (l0 + j) * 4);
        woB[j] = *(const v4f*)(W_out + (32 + l0 + j) * 4);
    }

    __syncthreads();

    const size_t row0 = (size_t)blockIdx.x * ROWS_PER_BLOCK + rid;
    const float* p = z_e + row0 * LATENT + l0;

    v4f vA = ldnt4(p);
    v4f vB = ldnt4(p + 32);

    for (int it = 0; it < NITER; ++it) {
        v4f nA, nB;
        if (it + 1 < NITER) {
            const float* pn = p + (size_t)(it + 1) * ROWS_PER_ITER * LATENT;
            nA = ldnt4(pn);
            nB = ldnt4(pn + 32);
        }

        // partial dots over this lane's 16 columns
        float s0 = dot8(vA, winA[0], vB, winB[0]);
        float s1 = dot8(vA, winA[1], vB, winB[1]);
        float s2 = dot8(vA, winA[2], vB, winB[2]);
        float s3 = dot8(vA, winA[3], vB, winB[3]);

        // 3-stage butterfly across the 8 lanes sharing this row
        #pragma unroll
        for (int m = 1; m < LANES_PER_ROW; m <<= 1) {
            s0 += __shfl_xor(s0, m);
            s1 += __shfl_xor(s1, m);
            s2 += __shfl_xor(s2, m);
            s3 += __shfl_xor(s3, m);
        }

        // FSQ quantization (levels 8,8,8,2) — redundant across the 8 lanes (free under SIMT)
        int b0, b1, b2;
        const float c0 = q7(s0, b0);
        const float c1 = q7(s1, b1);
        const float c2 = q7(s2, b2);
        // level-2 component: zs = (tanh(s3)+1)*0.5, boundary at s3==0, rint(0.5)==0
        const int   b3 = (s3 > 0.0f) ? 1 : 0;
        const float c3 = (float)b3 - 0.5f;

        // proj_out for this lane's 16 columns
        v4f oA, oB;
        oA.x = fmaf(c0, woA[0].x, fmaf(c1, woA[0].y, fmaf(c2, woA[0].z, c3 * woA[0].w)));
        oA.y = fmaf(c0, woA[1].x, fmaf(c1, woA[1].y, fmaf(c2, woA[1].z, c3 * woA[1].w)));
        oA.z = fmaf(c0, woA[2].x, fmaf(c1, woA[2].y, fmaf(c2, woA[2].z, c3 * woA[2].w)));
        oA.w = fmaf(c0, woA[3].x, fmaf(c1, woA[3].y, fmaf(c2, woA[3].z, c3 * woA[3].w)));
        oB.x = fmaf(c0, woB[0].x, fmaf(c1, woB[0].y, fmaf(c2, woB[0].z, c3 * woB[0].w)));
        oB.y = fmaf(c0, woB[1].x, fmaf(c1, woB[1].y, fmaf(c2, woB[1].z, c3 * woB[1].w)));
        oB.z = fmaf(c0, woB[2].x, fmaf(c1, woB[2].y, fmaf(c2, woB[2].z, c3 * woB[2].w)));
        oB.w = fmaf(c0, woB[3].x, fmaf(c1, woB[3].y, fmaf(c2, woB[3].z, c3 * woB[3].w)));

        const size_t row = row0 + (size_t)it * ROWS_PER_ITER;
        float* q = z_q + row * LATENT + l0;
        stnt4(q, oA);
        stnt4(q + 32, oB);

        if (sub == 0) {
            const int idx = b0 + (b1 << 3) + (b2 << 6) + (b3 << 9);
            atomicAdd(&lhist[idx], 1u);
            __builtin_nontemporal_store((float)idx, idx_out + row);
        }

        vA = nA;
        vB = nB;
    }

    __syncthreads();

    if (atomic_flush) {
        for (int i = tid; i < NUM_CODES; i += BLOCK) {
            const unsigned int c = lhist[i];
            if (c) atomicAdd(&counts[i], c);
        }
    } else {
        unsigned int* dst = hists + (size_t)blockIdx.x * NUM_CODES;
        for (int i = tid; i < NUM_CODES; i += BLOCK) dst[i] = lhist[i];
    }
}

// Reduce GRID partial hists -> counts[1024]. 128 blocks x 256 threads,
// each block sums 8 hists with fully coalesced reads, then 4 atomics/thread.
#define RED_BLOCKS 128
#define HISTS_PER_RED (GRID / RED_BLOCKS)   // 8

__global__ __launch_bounds__(256) void reduce_hist(
    const unsigned int* __restrict__ hists,
    unsigned int* __restrict__ counts)
{
    const int t = threadIdx.x;
    unsigned int a0 = 0, a1 = 0, a2 = 0, a3 = 0;
    const int k0 = blockIdx.x * HISTS_PER_RED;
    for (int k = k0; k < k0 + HISTS_PER_RED; ++k) {
        const unsigned int* h = hists + (size_t)k * NUM_CODES;
        a0 += h[t];
        a1 += h[t + 256];
        a2 += h[t + 512];
        a3 += h[t + 768];
    }
    atomicAdd(&counts[t], a0);
    atomicAdd(&counts[t + 256], a1);
    atomicAdd(&counts[t + 512], a2);
    atomicAdd(&counts[t + 768], a3);
}

__global__ __launch_bounds__(1024) void fsq_stats(
    const unsigned int* __restrict__ counts,
    float* __restrict__ out_scalars)   // 4 floats
{
    const int tid = threadIdx.x;   // one per code
    const unsigned int c = counts[tid];

    const float p = (float)c / (float)NROWS;
    double t = (double)(p * logf(p + 1e-10f));
    int nz = (c != 0) ? 1 : 0;

    #pragma unroll
    for (int off = 32; off > 0; off >>= 1) {
        t  += __shfl_down(t, off);
        nz += __shfl_down(nz, off);
    }
    __shared__ double sh_t[16];
    __shared__ int    sh_nz[16];
    const int wid = tid >> 6;
    if ((tid & 63) == 0) { sh_t[wid] = t; sh_nz[wid] = nz; }
    __syncthreads();
    if (tid == 0) {
        double T = 0.0; int N = 0;
        #pragma unroll
        for (int i = 0; i < 16; ++i) { T += sh_t[i]; N += sh_nz[i]; }
        out_scalars[0] = 0.0f;                        // commitment_loss
        out_scalars[1] = 0.0f;                        // codebook_loss
        out_scalars[2] = expf((float)(-T));           // perplexity
        out_scalars[3] = (float)N / (float)NUM_CODES; // utilization
    }
}

extern "C" void kernel_launch(void* const* d_in, const int* in_sizes, int n_in,
                              void* d_out, int out_size, void* d_ws, size_t ws_size,
                              hipStream_t stream) {
    const float* z_e   = (const float*)d_in[0];
    const float* W_in  = (const float*)d_in[1];
    const float* W_out = (const float*)d_in[2];

    float* out     = (float*)d_out;
    float* zq      = out;                          // B*64
    float* idxs    = out + (size_t)NROWS * LATENT; // B
    float* scalars = idxs + NROWS;                 // 4

    unsigned int* counts = (unsigned int*)d_ws;        // 1024
    unsigned int* hists  = counts + NUM_CODES;         // GRID*1024

    const size_t need = (size_t)(GRID + 1) * NUM_CODES * sizeof(unsigned int);
    if (ws_size >= need) {
        fsq_main<<<GRID, BLOCK, 0, stream>>>(z_e, W_in, W_out, zq, idxs,
                                             counts, hists, /*atomic_flush=*/0);
        reduce_hist<<<RED_BLOCKS, 256, 0, stream>>>(hists, counts);
    } else {
        hipMemsetAsync(d_ws, 0, NUM_CODES * sizeof(unsigned int), stream);
        fsq_main<<<GRID, BLOCK, 0, stream>>>(z_e, W_in, W_out, zq, idxs,
                                             counts, hists, /*atomic_flush=*/1);
    }
    fsq_stats<<<1, 1024, 0, stream>>>(counts, scalars);
}

// Round 3
// 241.558 us; speedup vs baseline: 1.6314x; 1.0070x over previous
//
#include <hip/hip_runtime.h>
#include <math.h>

#define NROWS 524288
#define LATENT 64
#define NUM_CODES 1024
#define BLOCK 256
#define GRID 1024
#define ROWS_PER_BLOCK (NROWS / GRID)            // 512
#define LANES_PER_ROW 8
#define ROWS_PER_ITER 64                         // 2 rows per thread per iter
#define NITER (ROWS_PER_BLOCK / ROWS_PER_ITER)   // 8

typedef float v4f __attribute__((ext_vector_type(4)));

__device__ __forceinline__ v4f ldnt4(const float* p) {
    return __builtin_nontemporal_load((const v4f*)p);
}
__device__ __forceinline__ void stnt4(float* p, v4f v) {
    __builtin_nontemporal_store(v, (v4f*)p);
}

__device__ __forceinline__ float dot8(v4f a, v4f wa, v4f b, v4f wb) {
    float r = a.x * wa.x;
    r = fmaf(a.y, wa.y, r); r = fmaf(a.z, wa.z, r); r = fmaf(a.w, wa.w, r);
    r = fmaf(b.x, wb.x, r); r = fmaf(b.y, wb.y, r);
    r = fmaf(b.z, wb.z, r); r = fmaf(b.w, wb.w, r);
    return r;
}

// Quantize one level-8 component (rintf = round half-to-even, matches jnp.round).
__device__ __forceinline__ float q7(float s, int& bin) {
    float t  = tanhf(s);
    float zs = (t + 1.0f) * 0.5f * 7.0f;
    float r  = rintf(zs);
    r = fminf(fmaxf(r, 0.0f), 7.0f);
    bin = (int)r;
    return r - 3.5f;
}

struct RowRes { v4f oA, oB; int idx; };

__device__ __forceinline__ RowRes process_row(
    v4f vA, v4f vB,
    const v4f winA[4], const v4f winB[4],
    const v4f woA[4], const v4f woB[4])
{
    float s0 = dot8(vA, winA[0], vB, winB[0]);
    float s1 = dot8(vA, winA[1], vB, winB[1]);
    float s2 = dot8(vA, winA[2], vB, winB[2]);
    float s3 = dot8(vA, winA[3], vB, winB[3]);

    #pragma unroll
    for (int m = 1; m < LANES_PER_ROW; m <<= 1) {
        s0 += __shfl_xor(s0, m);
        s1 += __shfl_xor(s1, m);
        s2 += __shfl_xor(s2, m);
        s3 += __shfl_xor(s3, m);
    }

    int b0, b1, b2;
    const float c0 = q7(s0, b0);
    const float c1 = q7(s1, b1);
    const float c2 = q7(s2, b2);
    // level-2 component: boundary at s3==0; rint(0.5)==0 so strict > is correct
    const int   b3 = (s3 > 0.0f) ? 1 : 0;
    const float c3 = (float)b3 - 0.5f;

    RowRes r;
    r.oA.x = fmaf(c0, woA[0].x, fmaf(c1, woA[0].y, fmaf(c2, woA[0].z, c3 * woA[0].w)));
    r.oA.y = fmaf(c0, woA[1].x, fmaf(c1, woA[1].y, fmaf(c2, woA[1].z, c3 * woA[1].w)));
    r.oA.z = fmaf(c0, woA[2].x, fmaf(c1, woA[2].y, fmaf(c2, woA[2].z, c3 * woA[2].w)));
    r.oA.w = fmaf(c0, woA[3].x, fmaf(c1, woA[3].y, fmaf(c2, woA[3].z, c3 * woA[3].w)));
    r.oB.x = fmaf(c0, woB[0].x, fmaf(c1, woB[0].y, fmaf(c2, woB[0].z, c3 * woB[0].w)));
    r.oB.y = fmaf(c0, woB[1].x, fmaf(c1, woB[1].y, fmaf(c2, woB[1].z, c3 * woB[1].w)));
    r.oB.z = fmaf(c0, woB[2].x, fmaf(c1, woB[2].y, fmaf(c2, woB[2].z, c3 * woB[2].w)));
    r.oB.w = fmaf(c0, woB[3].x, fmaf(c1, woB[3].y, fmaf(c2, woB[3].z, c3 * woB[3].w)));
    r.idx = b0 + (b1 << 3) + (b2 << 6) + (b3 << 9);
    return r;
}

__global__ __launch_bounds__(BLOCK, 4) void fsq_main(
    const float* __restrict__ z_e,    // (B, 64)
    const float* __restrict__ W_in,   // (4, 64) row-major
    const float* __restrict__ W_out,  // (64, 4) row-major
    float* __restrict__ z_q,          // (B, 64)
    float* __restrict__ idx_out,      // (B) stored as float
    unsigned int* __restrict__ counts)// (1024) pre-zeroed; global atomic flush
{
    __shared__ unsigned int lhist[NUM_CODES];
    const int tid = threadIdx.x;
    for (int i = tid; i < NUM_CODES; i += BLOCK) lhist[i] = 0;

    const int sub = tid & (LANES_PER_ROW - 1);  // lane within 8-lane row group
    const int rid = tid >> 3;                   // row slot (0..31)
    const int l0  = sub * 4;                    // fragment A col; B is +32

    v4f winA[4], winB[4], woA[4], woB[4];
    #pragma unroll
    for (int f = 0; f < 4; ++f) {
        winA[f] = *(const v4f*)(W_in + f * LATENT + l0);
        winB[f] = *(const v4f*)(W_in + f * LATENT + 32 + l0);
    }
    #pragma unroll
    for (int j = 0; j < 4; ++j) {
        woA[j] = *(const v4f*)(W_out + (l0 + j) * 4);
        woB[j] = *(const v4f*)(W_out + (32 + l0 + j) * 4);
    }

    __syncthreads();

    // Thread handles rows (base+rid) and (base+rid+32) each iteration.
    const size_t rowA0 = (size_t)blockIdx.x * ROWS_PER_BLOCK + rid;
    const float* pA = z_e + rowA0 * LATENT + l0;
    const float* pB = pA + 32 * LATENT;

    v4f aA = ldnt4(pA), aB = ldnt4(pA + 32);   // row A fragments
    v4f bA = ldnt4(pB), bB = ldnt4(pB + 32);   // row B fragments

    for (int it = 0; it < NITER; ++it) {
        v4f naA, naB, nbA, nbB;
        const bool more = (it + 1 < NITER);
        if (more) {
            const float* qA = pA + (size_t)(it + 1) * ROWS_PER_ITER * LATENT;
            const float* qB = qA + 32 * LATENT;
            naA = ldnt4(qA); naB = ldnt4(qA + 32);
            nbA = ldnt4(qB); nbB = ldnt4(qB + 32);
        }

        const RowRes rA = process_row(aA, aB, winA, winB, woA, woB);
        const RowRes rB = process_row(bA, bB, winA, winB, woA, woB);

        const size_t rowA = rowA0 + (size_t)it * ROWS_PER_ITER;
        const size_t rowB = rowA + 32;
        float* qa = z_q + rowA * LATENT + l0;
        float* qb = z_q + rowB * LATENT + l0;
        stnt4(qa, rA.oA);       stnt4(qa + 32, rA.oB);
        stnt4(qb, rB.oA);       stnt4(qb + 32, rB.oB);

        if (sub == 0) {
            atomicAdd(&lhist[rA.idx], 1u);
            atomicAdd(&lhist[rB.idx], 1u);
            idx_out[rowA] = (float)rA.idx;
            idx_out[rowB] = (float)rB.idx;
        }

        if (more) { aA = naA; aB = naB; bA = nbA; bB = nbB; }
    }

    __syncthreads();

    // Direct device-scope flush: each code gets <= GRID adds total.
    for (int i = tid; i < NUM_CODES; i += BLOCK) {
        const unsigned int c = lhist[i];
        if (c) atomicAdd(&counts[i], c);
    }
}

__global__ __launch_bounds__(1024) void fsq_stats(
    const unsigned int* __restrict__ counts,
    float* __restrict__ out_scalars)   // 4 floats
{
    const int tid = threadIdx.x;   // one per code
    const unsigned int c = counts[tid];

    const float p = (float)c / (float)NROWS;
    double t = (double)(p * logf(p + 1e-10f));
    int nz = (c != 0) ? 1 : 0;

    #pragma unroll
    for (int off = 32; off > 0; off >>= 1) {
        t  += __shfl_down(t, off);
        nz += __shfl_down(nz, off);
    }
    __shared__ double sh_t[16];
    __shared__ int    sh_nz[16];
    const int wid = tid >> 6;
    if ((tid & 63) == 0) { sh_t[wid] = t; sh_nz[wid] = nz; }
    __syncthreads();
    if (tid == 0) {
        double T = 0.0; int N = 0;
        #pragma unroll
        for (int i = 0; i < 16; ++i) { T += sh_t[i]; N += sh_nz[i]; }
        out_scalars[0] = 0.0f;                        // commitment_loss
        out_scalars[1] = 0.0f;                        // codebook_loss
        out_scalars[2] = expf((float)(-T));           // perplexity
        out_scalars[3] = (float)N / (float)NUM_CODES; // utilization
    }
}

extern "C" void kernel_launch(void* const* d_in, const int* in_sizes, int n_in,
                              void* d_out, int out_size, void* d_ws, size_t ws_size,
                              hipStream_t stream) {
    const float* z_e   = (const float*)d_in[0];
    const float* W_in  = (const float*)d_in[1];
    const float* W_out = (const float*)d_in[2];

    float* out     = (float*)d_out;
    float* zq      = out;                          // B*64
    float* idxs    = out + (size_t)NROWS * LATENT; // B
    float* scalars = idxs + NROWS;                 // 4

    unsigned int* counts = (unsigned int*)d_ws;    // 1024 (ws is poisoned 0xAA each call)

    hipMemsetAsync(counts, 0, NUM_CODES * sizeof(unsigned int), stream);
    fsq_main<<<GRID, BLOCK, 0, stream>>>(z_e, W_in, W_out, zq, idxs, counts);
    fsq_stats<<<1, 1024, 0, stream>>>(counts, scalars);
}